// Round 11
// baseline (230.469 us; speedup 1.0000x reference)
//
#include <hip/hip_runtime.h>
#include <hip/hip_fp16.h>
#include <cstddef>
#include <cstdint>

// N=50000, F_IN=128, HID=64, HEADS=4, E=800000, NG=64
// Layer1: x(fp32->fp16 in-reg)@W1p -> h1(fp16) + fused als1/ald1 via MFMA epilogue;
//         GAT agg (16B/lane, 2 edges/load) -> x2 fp16
// Layer2: x2@W2p -> h2(fp16) + fused als2/ald2; GAT agg (8 edges/load) -> out2 fp32
// Pool: segment-mean by sorted batch -> [64,64]; fc -> [64]

#define LOG2E 1.4426950408889634f
__device__ __forceinline__ float lrelu02(float x) { return x >= 0.f ? x : 0.2f * x; }
__device__ __forceinline__ float elu1(float x)    { return x > 0.f ? x : expm1f(x); }
__device__ __forceinline__ float fexp(float x)    { return exp2f(x * LOG2E); }

typedef _Float16 f16x8 __attribute__((ext_vector_type(8)));
typedef float    f32x4 __attribute__((ext_vector_type(4)));

// ---------------- CSR build (by destination) ----------------
__global__ void k_hist(const int* __restrict__ dst, int* __restrict__ cnt,
                       int* __restrict__ rank, int e) {
    int i = blockIdx.x * 256 + threadIdx.x;
    if (i < e) rank[i] = atomicAdd(&cnt[dst[i]], 1);
}

__global__ __launch_bounds__(1024) void k_scan1(const int* __restrict__ cnt,
                                                int* __restrict__ cscan,
                                                int* __restrict__ bsum, int n) {
    __shared__ int ws[16];
    const int t = threadIdx.x, lane = t & 63, wv = t >> 6;
    const int i = blockIdx.x * 1024 + t;
    int v = (i < n) ? cnt[i] : 0;
    int s = v;
#pragma unroll
    for (int d = 1; d < 64; d <<= 1) { int o = __shfl_up(s, d); if (lane >= d) s += o; }
    if (lane == 63) ws[wv] = s;
    __syncthreads();
    if (t < 16) {
        int xx = ws[t];
#pragma unroll
        for (int d = 1; d < 16; d <<= 1) { int o = __shfl_up(xx, d); if (t >= d) xx += o; }
        ws[t] = xx;
        if (t == 15) bsum[blockIdx.x] = xx;
    }
    __syncthreads();
    int incl = s + (wv > 0 ? ws[wv - 1] : 0);
    if (i < n) cscan[i] = incl;
}

__global__ __launch_bounds__(1024) void k_scan2(int* __restrict__ bsum, int nb) {
    __shared__ int ws[16];
    const int t = threadIdx.x, lane = t & 63, wv = t >> 6;
    int v = (t < nb) ? bsum[t] : 0;
    int s = v;
#pragma unroll
    for (int d = 1; d < 64; d <<= 1) { int o = __shfl_up(s, d); if (lane >= d) s += o; }
    if (lane == 63) ws[wv] = s;
    __syncthreads();
    if (t < 16) {
        int xx = ws[t];
#pragma unroll
        for (int d = 1; d < 16; d <<= 1) { int o = __shfl_up(xx, d); if (t >= d) xx += o; }
        ws[t] = xx;
    }
    __syncthreads();
    int incl = s + (wv > 0 ? ws[wv - 1] : 0);
    if (t < nb) bsum[t] = incl - v;   // exclusive
}

__global__ __launch_bounds__(1024) void k_scan3(const int* __restrict__ cscan,
                                                const int* __restrict__ bsum,
                                                int* __restrict__ rowptr, int n) {
    const int i = blockIdx.x * 1024 + threadIdx.x;
    if (i < n) rowptr[i + 1] = cscan[i] + bsum[blockIdx.x];
    if (i == 0) rowptr[0] = 0;
}

__global__ void k_scatter(const int* __restrict__ src, const int* __restrict__ dstArr,
                          const int* __restrict__ rank, const int* __restrict__ rowptr,
                          int* __restrict__ csr, int e) {
    int i = blockIdx.x * 256 + threadIdx.x;
    if (i < e) csr[rowptr[dstArr[i]] + rank[i]] = src[i];
}

// ---------------- W pack (both weights in one launch) ----------------
__device__ __forceinline__ void packOne(const float* __restrict__ W, __half* __restrict__ Bp,
                                        int K, int N, int i) {
    int c = i & 15, q = (i >> 4) & 3, tnt = i >> 6;
    int nt = tnt % (N / 16), t = tnt / (N / 16);
    int k0 = t * 32 + q * 8, col = nt * 16 + c;
    __half tmp[8];
#pragma unroll
    for (int j = 0; j < 8; ++j) tmp[j] = __float2half(W[(size_t)(k0 + j) * N + col]);
    *reinterpret_cast<int4*>(Bp + (size_t)i * 8) = *reinterpret_cast<int4*>(tmp);
}

__global__ void k_packW(const float* __restrict__ W1, __half* __restrict__ B1,
                        const float* __restrict__ W2, __half* __restrict__ B2) {
    int i = blockIdx.x * 256 + threadIdx.x;
    if (i < 4096) packOne(W1, B1, 128, 256, i);
    else if (i < 4096 + 2048) packOne(W2, B2, 256, 64, i - 4096);
}

// ---------------- MFMA GEMM + fused attention logits ----------------
template <int K, int N, bool AF32, int HEADS_>
__global__ __launch_bounds__(256) void k_gemm_mfma(const void* __restrict__ Av,
                                                   const __half* __restrict__ Bp,
                                                   __half* __restrict__ C,
                                                   const float* __restrict__ a_src,
                                                   const float* __restrict__ a_dst,
                                                   float* __restrict__ als,
                                                   float* __restrict__ ald, int M) {
    constexpr int NT = N / 16, KT = K / 32;
    const int lane = threadIdx.x & 63;
    const int wv = threadIdx.x >> 6;
    const int row0 = (blockIdx.x * 4 + wv) * 16;
    if (row0 >= M) return;

    f32x4 acc[NT];
#pragma unroll
    for (int nt = 0; nt < NT; ++nt) acc[nt] = (f32x4){0.f, 0.f, 0.f, 0.f};

    const __half* Ah = (const __half*)Av;
    const float*  Af = (const float*)Av;
    const size_t arow = (size_t)(row0 + (lane & 15)) * K + (lane >> 4) * 8;
    const __half* Bb = Bp + (size_t)lane * 8;
#pragma unroll
    for (int t = 0; t < KT; ++t) {
        f16x8 a;
        if constexpr (AF32) {
            float4 u0 = *reinterpret_cast<const float4*>(Af + arow + t * 32);
            float4 u1 = *reinterpret_cast<const float4*>(Af + arow + t * 32 + 4);
            a[0] = (_Float16)u0.x; a[1] = (_Float16)u0.y;
            a[2] = (_Float16)u0.z; a[3] = (_Float16)u0.w;
            a[4] = (_Float16)u1.x; a[5] = (_Float16)u1.y;
            a[6] = (_Float16)u1.z; a[7] = (_Float16)u1.w;
        } else {
            a = *reinterpret_cast<const f16x8*>(Ah + arow + t * 32);
        }
#pragma unroll
        for (int nt = 0; nt < NT; ++nt) {
            f16x8 b = *reinterpret_cast<const f16x8*>(Bb + (size_t)(t * NT + nt) * 512);
            acc[nt] = __builtin_amdgcn_mfma_f32_16x16x32_f16(a, b, acc[nt], 0, 0, 0);
        }
    }
    const int r0 = row0 + (lane >> 4) * 4;
    const int cl = lane & 15;
#pragma unroll
    for (int nt = 0; nt < NT; ++nt) {
        int col = nt * 16 + cl;
#pragma unroll
        for (int j = 0; j < 4; ++j)
            C[(size_t)(r0 + j) * N + col] = __float2half(acc[nt][j]);
    }
    float av[NT], dv[NT];
#pragma unroll
    for (int nt = 0; nt < NT; ++nt) {
        av[nt] = a_src[nt * 16 + cl];
        dv[nt] = a_dst[nt * 16 + cl];
    }
    constexpr int NTH = NT / HEADS_;
#pragma unroll
    for (int j = 0; j < 4; ++j) {
#pragma unroll
        for (int h = 0; h < HEADS_; ++h) {
            float ps = 0.f, pd = 0.f;
#pragma unroll
            for (int t = 0; t < NTH; ++t) {
                ps = fmaf(acc[h * NTH + t][j], av[h * NTH + t], ps);
                pd = fmaf(acc[h * NTH + t][j], dv[h * NTH + t], pd);
            }
#pragma unroll
            for (int d = 1; d < 16; d <<= 1) { ps += __shfl_xor(ps, d); pd += __shfl_xor(pd, d); }
            if (cl == 0) {
                int r = r0 + j;
                als[(size_t)r * HEADS_ + h] = ps;
                ald[(size_t)r * HEADS_ + h] = pd;
            }
        }
    }
}

// accumulate 8 halves (one float4 = 4x __half2) with scalar weight into acc[8]
__device__ __forceinline__ void h8acc(float4 v, float w, float* acc) {
    const __half2* hv = reinterpret_cast<const __half2*>(&v);
#pragma unroll
    for (int c = 0; c < 4; ++c) {
        acc[2 * c + 0] = fmaf(w, (float)__low2half(hv[c]),  acc[2 * c + 0]);
        acc[2 * c + 1] = fmaf(w, (float)__high2half(hv[c]), acc[2 * c + 1]);
    }
}

// ---------------- edge aggregation, layer 1 (16B/lane, 2 edges per load) ----------------
// Wave = 1 node. Lane covers 8 channels: ch8=(lane&31)*8; edge slot eslot=lane>>5.
// 8 virtual slots per iter (slot deg = self-loop), weights computed once per
// (edge,head) by lanes (e8=lane&7, h8=(lane>>3)&3) and bpermuted to consumers.
__global__ void k_edge1(const __half* __restrict__ h1, const float* __restrict__ als,
                        const float* __restrict__ ald, const int* __restrict__ rowptr,
                        const int* __restrict__ csr, const float* __restrict__ b1,
                        __half* __restrict__ x2, int n) {
    const int lane = threadIdx.x & 63;
    const int node = (blockIdx.x << 2) + (threadIdx.x >> 6);
    if (node >= n) return;
    const int eslot = lane >> 5;            // 0/1: which edge of the pair
    const int ch8 = (lane & 31) * 8;        // 8 channels per lane
    const int e8 = lane & 7, h8 = (lane >> 3) & 3;
    const float adh8 = ald[node * 4 + h8];
    const int slbase = (((lane & 31) >> 3) << 3) + eslot;  // weight source lane base
    float acc[8] = {0.f, 0.f, 0.f, 0.f, 0.f, 0.f, 0.f, 0.f};
    float wsum = 0.f;
    const int beg = rowptr[node];
    const int deg = rowptr[node + 1] - beg;
    for (int base = 0; base <= deg; base += 8) {
        // wave-uniform index loads -> scalars; slot >= deg maps to self node
        int s0 = (base + 0 < deg) ? csr[beg + base + 0] : node;
        int s1 = (base + 1 < deg) ? csr[beg + base + 1] : node;
        int s2 = (base + 2 < deg) ? csr[beg + base + 2] : node;
        int s3 = (base + 3 < deg) ? csr[beg + base + 3] : node;
        int s4 = (base + 4 < deg) ? csr[beg + base + 4] : node;
        int s5 = (base + 5 < deg) ? csr[beg + base + 5] : node;
        int s6 = (base + 6 < deg) ? csr[beg + base + 6] : node;
        int s7 = (base + 7 < deg) ? csr[beg + base + 7] : node;
        // 4 pair-loads: lane reads 16B of row s[2p+eslot]
        int p0 = eslot ? s1 : s0;
        int p1 = eslot ? s3 : s2;
        int p2 = eslot ? s5 : s4;
        int p3 = eslot ? s7 : s6;
        float4 v0 = *reinterpret_cast<const float4*>(h1 + (size_t)p0 * 256 + ch8);
        float4 v1 = *reinterpret_cast<const float4*>(h1 + (size_t)p1 * 256 + ch8);
        float4 v2 = *reinterpret_cast<const float4*>(h1 + (size_t)p2 * 256 + ch8);
        float4 v3 = *reinterpret_cast<const float4*>(h1 + (size_t)p3 * 256 + ch8);
        // weight chain (overlaps the loads)
        int se = s0;
        se = (e8 == 1) ? s1 : se; se = (e8 == 2) ? s2 : se; se = (e8 == 3) ? s3 : se;
        se = (e8 == 4) ? s4 : se; se = (e8 == 5) ? s5 : se; se = (e8 == 6) ? s6 : se;
        se = (e8 == 7) ? s7 : se;
        float myw = (base + e8 <= deg)
                        ? fexp(lrelu02(als[(size_t)se * 4 + h8] + adh8)) : 0.f;
        float w0 = __shfl(myw, slbase + 0);
        float w1 = __shfl(myw, slbase + 2);
        float w2 = __shfl(myw, slbase + 4);
        float w3 = __shfl(myw, slbase + 6);
        h8acc(v0, w0, acc);
        h8acc(v1, w1, acc);
        h8acc(v2, w2, acc);
        h8acc(v3, w3, acc);
        wsum += (w0 + w1) + (w2 + w3);
    }
    // combine the two edge halves
#pragma unroll
    for (int c = 0; c < 8; ++c) acc[c] += __shfl_xor(acc[c], 32);
    wsum += __shfl_xor(wsum, 32);
    if (eslot == 0) {
        const float inv = 1.f / (wsum + 1e-16f);
        float4 b0 = *reinterpret_cast<const float4*>(b1 + ch8);
        float4 b4 = *reinterpret_cast<const float4*>(b1 + ch8 + 4);
        float o[8];
        o[0] = elu1(acc[0] * inv + b0.x); o[1] = elu1(acc[1] * inv + b0.y);
        o[2] = elu1(acc[2] * inv + b0.z); o[3] = elu1(acc[3] * inv + b0.w);
        o[4] = elu1(acc[4] * inv + b4.x); o[5] = elu1(acc[5] * inv + b4.y);
        o[6] = elu1(acc[6] * inv + b4.z); o[7] = elu1(acc[7] * inv + b4.w);
        __half2 q0 = __floats2half2_rn(o[0], o[1]);
        __half2 q1 = __floats2half2_rn(o[2], o[3]);
        __half2 q2 = __floats2half2_rn(o[4], o[5]);
        __half2 q3 = __floats2half2_rn(o[6], o[7]);
        int4 p;
        p.x = *reinterpret_cast<int*>(&q0); p.y = *reinterpret_cast<int*>(&q1);
        p.z = *reinterpret_cast<int*>(&q2); p.w = *reinterpret_cast<int*>(&q3);
        *reinterpret_cast<int4*>(x2 + (size_t)node * 256 + ch8) = p;
    }
}

// ---------------- edge aggregation, layer 2 (16B/lane, 8 edges per load) ----------------
// Wave = 1 node. Lane covers 8 of 64 channels: ch8=(lane&7)*8; edge slot = lane>>3.
__global__ void k_edge2(const __half* __restrict__ h2, const float* __restrict__ als,
                        const float* __restrict__ ald, const int* __restrict__ rowptr,
                        const int* __restrict__ csr, const float* __restrict__ b2,
                        float* __restrict__ out2, int n) {
    const int lane = threadIdx.x & 63;
    const int node = (blockIdx.x << 2) + (threadIdx.x >> 6);
    if (node >= n) return;
    const int eslot = lane >> 3;            // 0..7: edge slot
    const int ch8 = (lane & 7) * 8;         // 8 channels per lane
    const int e8 = lane & 7;
    const float adl = ald[node];
    float acc[8] = {0.f, 0.f, 0.f, 0.f, 0.f, 0.f, 0.f, 0.f};
    float wsum = 0.f;
    const int beg = rowptr[node];
    const int deg = rowptr[node + 1] - beg;
    for (int base = 0; base <= deg; base += 8) {
        int s0 = (base + 0 < deg) ? csr[beg + base + 0] : node;
        int s1 = (base + 1 < deg) ? csr[beg + base + 1] : node;
        int s2 = (base + 2 < deg) ? csr[beg + base + 2] : node;
        int s3 = (base + 3 < deg) ? csr[beg + base + 3] : node;
        int s4 = (base + 4 < deg) ? csr[beg + base + 4] : node;
        int s5 = (base + 5 < deg) ? csr[beg + base + 5] : node;
        int s6 = (base + 6 < deg) ? csr[beg + base + 6] : node;
        int s7 = (base + 7 < deg) ? csr[beg + base + 7] : node;
        // per-lane row select (slot eslot) and one 16B load -> 8 rows per wave
        int sp = s0;
        sp = (eslot == 1) ? s1 : sp; sp = (eslot == 2) ? s2 : sp; sp = (eslot == 3) ? s3 : sp;
        sp = (eslot == 4) ? s4 : sp; sp = (eslot == 5) ? s5 : sp; sp = (eslot == 6) ? s6 : sp;
        sp = (eslot == 7) ? s7 : sp;
        float4 v = *reinterpret_cast<const float4*>(h2 + (size_t)sp * 64 + ch8);
        // weight for slot e8 computed by this lane, consumed from lane eslot
        int se = s0;
        se = (e8 == 1) ? s1 : se; se = (e8 == 2) ? s2 : se; se = (e8 == 3) ? s3 : se;
        se = (e8 == 4) ? s4 : se; se = (e8 == 5) ? s5 : se; se = (e8 == 6) ? s6 : se;
        se = (e8 == 7) ? s7 : se;
        float myw = (base + e8 <= deg) ? fexp(lrelu02(als[se] + adl)) : 0.f;
        float w = __shfl(myw, eslot);
        h8acc(v, w, acc);
        wsum += w;
    }
    // reduce across the 8 edge slots (lane bits 3..5)
#pragma unroll
    for (int st = 8; st < 64; st <<= 1) {
#pragma unroll
        for (int c = 0; c < 8; ++c) acc[c] += __shfl_xor(acc[c], st);
        wsum += __shfl_xor(wsum, st);
    }
    if (eslot == 0) {
        const float inv = 1.f / (wsum + 1e-16f);
        float4 o0, o1;
        o0.x = elu1(acc[0] * inv + b2[ch8 + 0]);
        o0.y = elu1(acc[1] * inv + b2[ch8 + 1]);
        o0.z = elu1(acc[2] * inv + b2[ch8 + 2]);
        o0.w = elu1(acc[3] * inv + b2[ch8 + 3]);
        o1.x = elu1(acc[4] * inv + b2[ch8 + 4]);
        o1.y = elu1(acc[5] * inv + b2[ch8 + 5]);
        o1.z = elu1(acc[6] * inv + b2[ch8 + 6]);
        o1.w = elu1(acc[7] * inv + b2[ch8 + 7]);
        *reinterpret_cast<float4*>(out2 + (size_t)node * 64 + ch8) = o0;
        *reinterpret_cast<float4*>(out2 + (size_t)node * 64 + ch8 + 4) = o1;
    }
}

// ---------------- pool (mean by sorted batch) + fc ----------------
__global__ __launch_bounds__(1024) void k_pool(const float* __restrict__ out2,
                                               const int* __restrict__ batch,
                                               const float* __restrict__ fcW,
                                               const float* __restrict__ fcb,
                                               float* __restrict__ out, int n) {
    __shared__ float sbuf[16][64];
    const int g = blockIdx.x;
    const int lane = threadIdx.x & 63, wv = threadIdx.x >> 6;
    int lo0 = 0, hi0 = n;
    while (lo0 < hi0) { int mid = (lo0 + hi0) >> 1; if (batch[mid] < g) lo0 = mid + 1; else hi0 = mid; }
    int lo1 = lo0, hi1 = n;
    while (lo1 < hi1) { int mid = (lo1 + hi1) >> 1; if (batch[mid] < g + 1) lo1 = mid + 1; else hi1 = mid; }
    float s0 = 0.f, s1 = 0.f;
    int r = lo0 + wv;
    for (; r + 16 < lo1; r += 32) {
        s0 += out2[(size_t)r * 64 + lane];
        s1 += out2[(size_t)(r + 16) * 64 + lane];
    }
    if (r < lo1) s0 += out2[(size_t)r * 64 + lane];
    sbuf[wv][lane] = s0 + s1;
    __syncthreads();
    if (wv == 0) {
        float s = 0.f;
#pragma unroll
        for (int k = 0; k < 16; ++k) s += sbuf[k][lane];
        float cntf = (float)(lo1 - lo0);
        float pooled = s / fmaxf(cntf, 1.f);
        float v = pooled * fcW[lane];
#pragma unroll
        for (int d = 32; d; d >>= 1) v += __shfl_xor(v, d);
        if (lane == 0) out[g] = v + fcb[0];
    }
}

// ---------------- host launcher ----------------
extern "C" void kernel_launch(void* const* d_in, const int* in_sizes, int n_in,
                              void* d_out, int out_size, void* d_ws, size_t ws_size,
                              hipStream_t stream) {
    const float* x      = (const float*)d_in[0];
    const int*   ei     = (const int*)  d_in[1];
    const int*   batch  = (const int*)  d_in[2];
    const float* W1     = (const float*)d_in[3];
    const float* a_src1 = (const float*)d_in[4];
    const float* a_dst1 = (const float*)d_in[5];
    const float* b1     = (const float*)d_in[6];
    const float* W2     = (const float*)d_in[7];
    const float* a_src2 = (const float*)d_in[8];
    const float* a_dst2 = (const float*)d_in[9];
    const float* b2     = (const float*)d_in[10];
    const float* fcW    = (const float*)d_in[11];
    const float* fcb    = (const float*)d_in[12];
    float* out = (float*)d_out;

    const int N = in_sizes[2];
    const int E = in_sizes[1] / 2;
    (void)n_in; (void)ws_size;

    char* ws = (char*)d_ws;
    size_t off = 0;
    auto alloc = [&](size_t bytes) -> char* {
        char* p = ws + off;
        off += (bytes + 255) & ~(size_t)255;
        return p;
    };
    int*    cnt    = (int*)   alloc((size_t)N * 4);
    int*    cscan  = (int*)   alloc((size_t)N * 4);
    int*    bsum   = (int*)   alloc((size_t)1024 * 4);
    int*    rank   = (int*)   alloc((size_t)E * 4);
    int*    rowptr = (int*)   alloc((size_t)(N + 1) * 4);
    int*    csr    = (int*)   alloc((size_t)(E + 8) * 4);
    __half* W1p    = (__half*)alloc((size_t)128 * 256 * 2);
    __half* W2p    = (__half*)alloc((size_t)256 * 64 * 2);
    __half* h1h    = (__half*)alloc((size_t)N * 256 * 2);
    __half* x2h    = (__half*)alloc((size_t)N * 256 * 2);
    __half* h2h    = (__half*)alloc((size_t)N * 64 * 2);
    float*  out2   = (float*) alloc((size_t)N * 64 * 4);
    float*  als1   = (float*) alloc((size_t)N * 4 * 4);
    float*  ald1   = (float*) alloc((size_t)N * 4 * 4);
    float*  als2   = (float*) alloc((size_t)N * 4);
    float*  ald2   = (float*) alloc((size_t)N * 4);

    hipMemsetAsync(cnt, 0, (size_t)N * 4, stream);
    const int ge = (E + 255) / 256;
    const int nb = (N + 1023) / 1024;
    k_hist<<<ge, 256, 0, stream>>>(ei + E, cnt, rank, E);
    k_scan1<<<nb, 1024, 0, stream>>>(cnt, cscan, bsum, N);
    k_scan2<<<1, 1024, 0, stream>>>(bsum, nb);
    k_scan3<<<nb, 1024, 0, stream>>>(cscan, bsum, rowptr, N);
    k_scatter<<<ge, 256, 0, stream>>>(ei, ei + E, rank, rowptr, csr, E);

    // weight packing (both layers, one launch)
    k_packW<<<24, 256, 0, stream>>>(W1, W1p, W2, W2p);

    // Layer 1: MFMA GEMM [N,128](fp32 A)@[128,256] -> fp16 h1 + fused als1/ald1
    const int gw = (N / 16 + 3) / 4;
    const int gn4 = (N + 3) / 4;
    k_gemm_mfma<128, 256, true, 4><<<gw, 256, 0, stream>>>(x, W1p, h1h,
                                                           a_src1, a_dst1, als1, ald1, N);
    k_edge1<<<gn4, 256, 0, stream>>>(h1h, als1, ald1, rowptr, csr, b1, x2h, N);

    // Layer 2: MFMA GEMM [N,256]@[256,64] -> fp16 h2 + fused als2/ald2
    k_gemm_mfma<256, 64, false, 1><<<gw, 256, 0, stream>>>(x2h, W2p, h2h,
                                                           a_src2, a_dst2, als2, ald2, N);
    k_edge2<<<gn4, 256, 0, stream>>>(h2h, als2, ald2, rowptr, csr, b2, out2, N);

    // Pool + FC
    k_pool<<<out_size, 1024, 0, stream>>>(out2, batch, fcW, fcb, out, N);
}